// Round 9
// baseline (416.564 us; speedup 1.0000x reference)
//
#include <hip/hip_runtime.h>
#include <cmath>

// BlockwiseEarlyExitMamba: output depends only on feat[:,31,:] -> compute T=32 tokens.
#define TT 32
#define NTOK 512   // BATCH*TT
#define DM 256
#define DI 512

typedef float vf4 __attribute__((ext_vector_type(4)));

__device__ __forceinline__ float silu_(float x){ return x / (1.f + __expf(-x)); }

#define FMA16() do { \
  acc[0][0] += xv.x*wv.x; acc[0][1] += xv.x*wv.y; acc[0][2] += xv.x*wv.z; acc[0][3] += xv.x*wv.w; \
  acc[1][0] += xv.y*wv.x; acc[1][1] += xv.y*wv.y; acc[1][2] += xv.y*wv.z; acc[1][3] += xv.y*wv.w; \
  acc[2][0] += xv.z*wv.x; acc[2][1] += xv.z*wv.y; acc[2][2] += xv.z*wv.z; acc[2][3] += xv.z*wv.w; \
  acc[3][0] += xv.w*wv.x; acc[3][1] += xv.w*wv.y; acc[3][2] += xv.w*wv.z; acc[3][3] += xv.w*wv.w; \
} while(0)

// ---------- frontend: embed -> fusion GEMM (K=136) -> raw s0 (verified) ------
__global__ __launch_bounds__(128)
void k_front(const float* __restrict__ x,
             const float* __restrict__ ep, const float* __restrict__ ef,
             const float* __restrict__ ed,
             const float* __restrict__ plw, const float* __restrict__ plb,
             const float* __restrict__ piw, const float* __restrict__ pib,
             const float* __restrict__ fw,  const float* __restrict__ fb,
             float* __restrict__ s0)
{
  __shared__ float Xs[136*36];
  __shared__ float Ws[136*68];
  int bb = blockIdx.y;
  int n0 = blockIdx.x*64;
  int tid = threadIdx.x;
  for (int r = 0; r < 34; ++r){
    int idx = r*128 + tid;
    int t = idx & 31, j = idx >> 5;
    const float* xr = x + ((size_t)(bb*1024 + t))*5;
    float v;
    if      (j <  32){ int i = __float2int_rz(xr[0]); i = min(max(i,0),255); v = ep[i*32 + j]; }
    else if (j <  64){ v = xr[1]*plw[j-32] + plb[j-32]; }
    else if (j <  96){ int i = __float2int_rz(xr[2]); i = min(max(i,0),63);  v = ef[i*32 + (j-64)]; }
    else if (j < 128){ v = xr[3]*piw[j-96] + pib[j-96]; }
    else             { int i = __float2int_rz(xr[4]); i = min(max(i,0),1);   v = ed[i*8 + (j-128)]; }
    Xs[j*36 + t] = v;
  }
  {
    int c = tid >> 1, jh = tid & 1;
    const float4* src = (const float4*)(fw + (size_t)(n0 + c)*136 + jh*68);
    #pragma unroll
    for (int q = 0; q < 17; ++q){
      float4 v = src[q];
      int j = jh*68 + q*4;
      Ws[(j+0)*68 + c] = v.x; Ws[(j+1)*68 + c] = v.y;
      Ws[(j+2)*68 + c] = v.z; Ws[(j+3)*68 + c] = v.w;
    }
  }
  __syncthreads();
  int my = tid >> 4, nx = tid & 15;
  float acc[4][4] = {};
  #pragma unroll 4
  for (int k = 0; k < 136; ++k){
    float4 xv = *(const float4*)&Xs[k*36 + my*4];
    float4 wv = *(const float4*)&Ws[k*68 + nx*4];
    FMA16();
  }
  #pragma unroll
  for (int i = 0; i < 4; ++i){
    int t = my*4 + i;
    float4 o;
    o.x = acc[i][0] + fb[n0 + nx*4 + 0];
    o.y = acc[i][1] + fb[n0 + nx*4 + 1];
    o.z = acc[i][2] + fb[n0 + nx*4 + 2];
    o.w = acc[i][3] + fb[n0 + nx*4 + 3];
    *(float4*)&s0[(size_t)(bb*32 + t)*DM + n0 + nx*4] = o;
  }
}

// ---------------- k_ip: LN(resid [+featPrev]) + in_proj + conv/silu + xp-partials
// grid (16 ntiles, 16 batches), 128 thr; ntile<8 -> x channels, >=8 -> z channels
__global__ __launch_bounds__(128)
void k_ip(const float* __restrict__ wip, const float* __restrict__ cwl,
          const float* __restrict__ cbl, const float* __restrict__ xpl,
          const float* __restrict__ g, const float* __restrict__ bb,
          const float* __restrict__ resid, const float* __restrict__ featPrev,
          float* __restrict__ featOut, float* __restrict__ accZ,
          float* __restrict__ pxp, float* __restrict__ xcT, float* __restrict__ zsT)
{
  __shared__ float featT[256*36];   // [k 0..255][t 0..31]
  __shared__ float WA[4352];        // LN-red / W chunk [64][68] / sxz[32][68]+xcl[32][68]
  int tid = threadIdx.x;
  int nb = blockIdx.x, b = blockIdx.y;
  int n0 = nb*64;

  // ---- LN pass 1: raw residual sums into featT + per-token stats ----
  {
    int t = tid & 31, cg = tid >> 5;       // cg 0..3, each 64 channels
    size_t base = (size_t)(b*32 + t)*DM + cg*64;
    float s = 0.f, sq = 0.f;
    #pragma unroll
    for (int q = 0; q < 16; ++q){
      float4 v = *(const float4*)&resid[base + q*4];
      if (featPrev){
        float4 u = *(const float4*)&featPrev[base + q*4];
        v.x += u.x; v.y += u.y; v.z += u.z; v.w += u.w;
      }
      int c = cg*64 + q*4;
      featT[(c+0)*36 + t] = v.x; featT[(c+1)*36 + t] = v.y;
      featT[(c+2)*36 + t] = v.z; featT[(c+3)*36 + t] = v.w;
      s += v.x+v.y+v.z+v.w;
      sq += v.x*v.x+v.y*v.y+v.z*v.z+v.w*v.w;
    }
    WA[t*4 + cg] = s;
    WA[128 + t*4 + cg] = sq;
  }
  __syncthreads();
  // ---- LN pass 2: normalize in place; ntile 0 writes featOut; zero acc slice
  {
    int t = tid & 31, cg = tid >> 5;
    float S = WA[t*4+0]+WA[t*4+1]+WA[t*4+2]+WA[t*4+3];
    float Q = WA[128+t*4+0]+WA[128+t*4+1]+WA[128+t*4+2]+WA[128+t*4+3];
    float mu = S*(1.f/256.f), var = Q*(1.f/256.f) - mu*mu;
    float r = rsqrtf(var + 1e-5f);
    #pragma unroll 8
    for (int q = 0; q < 64; ++q){
      int c = cg*64 + q;
      float nv = (featT[c*36 + t] - mu)*r*g[c] + bb[c];
      featT[c*36 + t] = nv;
      if (nb == 0) featOut[(size_t)(b*32 + t)*DM + c] = nv;
    }
  }
  {
    int t = tid >> 2, j4 = (tid & 3)*4;
    float4 z4 = {0.f, 0.f, 0.f, 0.f};
    *(float4*)&accZ[(size_t)(b*32 + t)*DM + nb*16 + j4] = z4;
  }

  // ---- GEMM: tile 32 tok x 64 ch, K=256 in 4 chunks of 64 (round-2 verified) ----
  int my = tid >> 4, nx = tid & 15;
  float acc[4][4] = {};
  for (int kc = 0; kc < 4; ++kc){
    __syncthreads();
    {
      int c = tid >> 1, kh = tid & 1;
      const float4* src = (const float4*)(wip + (size_t)(n0+c)*DM + kc*64 + kh*32);
      #pragma unroll
      for (int q = 0; q < 8; ++q){
        float4 v = src[q];
        int k = kh*32 + q*4;
        WA[(k+0)*68 + c] = v.x; WA[(k+1)*68 + c] = v.y;
        WA[(k+2)*68 + c] = v.z; WA[(k+3)*68 + c] = v.w;
      }
    }
    __syncthreads();
    #pragma unroll 4
    for (int kk = 0; kk < 64; ++kk){
      int k = kc*64 + kk;
      float4 xv = *(const float4*)&featT[k*36 + my*4];
      float4 wv = *(const float4*)&WA[kk*68 + nx*4];
      FMA16();
    }
  }
  __syncthreads();
  { // acc -> sxz [32][68] (raw in_proj outputs for this 64-ch tile)
    #pragma unroll
    for (int i = 0; i < 4; ++i){
      vf4 o = {acc[i][0], acc[i][1], acc[i][2], acc[i][3]};
      *(vf4*)&WA[(my*4 + i)*68 + nx*4] = o;
    }
  }
  __syncthreads();

  // ---- conv+silu (x) / silu (z); coalesced transposed stores ----
  {
    int t = tid & 31, cg = tid >> 5;
    const float* sxz = WA;
    float* xcl = WA + 2176;
    if (n0 < 512){
      #pragma unroll
      for (int j = 0; j < 16; ++j){
        int c = cg*16 + j;
        int d = n0 + c;
        float4 k4 = *(const float4*)(cwl + (size_t)d*4);
        float a = cbl[d];
        if (t >= 3) a += k4.x*sxz[(t-3)*68 + c];
        if (t >= 2) a += k4.y*sxz[(t-2)*68 + c];
        if (t >= 1) a += k4.z*sxz[(t-1)*68 + c];
        a += k4.w*sxz[t*68 + c];
        float rx = silu_(a);
        xcl[t*68 + c] = rx;
        xcT[(size_t)d*NTOK + b*32 + t] = rx;
      }
    } else {
      #pragma unroll
      for (int j = 0; j < 16; ++j){
        int c = cg*16 + j;
        zsT[(size_t)(n0 - 512 + c)*NTOK + b*32 + t] = silu_(sxz[t*68 + c]);
      }
    }
  }
  __syncthreads();
  // ---- x_proj partials over this block's 64 dims (x-blocks only) ----
  if (n0 < 512){
    int t = tid & 31, cg = tid >> 5;
    const float* xcl = WA + 2176;
    #pragma unroll
    for (int jj = 0; jj < 12; ++jj){
      int c = cg*12 + jj;
      const float* wr = xpl + (size_t)c*DI + n0;
      float pa = 0.f;
      #pragma unroll 4
      for (int k4 = 0; k4 < 16; ++k4){
        vf4 xx = *(const vf4*)&xcl[t*68 + k4*4];
        pa += xx[0]*wr[k4*4] + xx[1]*wr[k4*4+1] + xx[2]*wr[k4*4+2] + xx[3]*wr[k4*4+3];
      }
      pxp[((size_t)(b*8 + nb)*48 + c)*32 + t] = pa;
    }
  }
}

// ---------------- k_sc: xp-reduce + dt + scan + gate + out_proj partial (atomic)
// grid (16 dslices of 32, 16 batches), 512 thr
__global__ __launch_bounds__(512)
void k_sc(const float* __restrict__ pxp,
          const float* __restrict__ dtwl, const float* __restrict__ dtbl,
          const float* __restrict__ alogl, const float* __restrict__ dprl,
          const float* __restrict__ opwl,
          const float* __restrict__ xcT, const float* __restrict__ zsT,
          float* __restrict__ accA)
{
  __shared__ float sdtr[32*18], sB[32*18], sC[32*18];
  __shared__ float sdt[32*33], sxv[32*33], szz[32*33];
  __shared__ float ygT[32*36];       // [d-local][t]
  __shared__ float Wop[32*260];      // [k][256 ch + pad]
  int tid = threadIdx.x;
  int ds = blockIdx.x, b = blockIdx.y;
  int d0 = ds*32;

  // ---- sum 8 x_proj partials -> dtr/B/C ----
  #pragma unroll
  for (int r = 0; r < 3; ++r){
    int o = r*512 + tid;               // 1536 outputs: c*32 + t
    int c = o >> 5, t = o & 31;
    size_t p0 = ((size_t)(b*8)*48 + c)*32 + t;
    float v = 0.f;
    #pragma unroll
    for (int nb = 0; nb < 8; ++nb) v += pxp[p0 + (size_t)nb*1536];
    if      (c < 16) sdtr[t*18 + c] = v;
    else if (c < 32) sB[t*18 + (c-16)] = v;
    else             sC[t*18 + (c-32)] = v;
  }
  // ---- stage xv, zz slices (from transposed buffers) ----
  {
    int dl = tid >> 4, t2 = (tid & 15)*2;
    size_t base = (size_t)(d0 + dl)*NTOK + b*32 + t2;
    float2 u = *(const float2*)&xcT[base];
    float2 w = *(const float2*)&zsT[base];
    sxv[t2*33 + dl] = u.x; sxv[(t2+1)*33 + dl] = u.y;
    szz[t2*33 + dl] = w.x; szz[(t2+1)*33 + dl] = w.y;
  }
  __syncthreads();
  // ---- dt = softplus(dtr @ dtw.T + dtb) ----
  {
    #pragma unroll
    for (int r = 0; r < 2; ++r){
      int idx = tid*2 + r;             // 1024 entries: t*32 + dl
      int t = idx >> 5, dl = idx & 31;
      int d = d0 + dl;
      const float4* dwr = (const float4*)(dtwl + (size_t)d*16);
      float4 a0 = dwr[0], a1 = dwr[1], a2 = dwr[2], a3 = dwr[3];
      const float* sr = &sdtr[t*18];
      float a = dtbl[d];
      a += a0.x*sr[0] + a0.y*sr[1] + a0.z*sr[2] + a0.w*sr[3];
      a += a1.x*sr[4] + a1.y*sr[5] + a1.z*sr[6] + a1.w*sr[7];
      a += a2.x*sr[8] + a2.y*sr[9] + a2.z*sr[10]+ a2.w*sr[11];
      a += a3.x*sr[12]+ a3.y*sr[13]+ a3.z*sr[14]+ a3.w*sr[15];
      sdt[t*33 + dl] = fmaxf(a, 0.f) + log1pf(expf(-fabsf(a)));
    }
  }
  __syncthreads();
  // ---- scan (32 d x 16 n) + D-skip + gate -> ygT (round-5 verified) ----
  {
    int dd = tid >> 4, nidx = tid & 15;
    int d = d0 + dd;
    float A = -expf(alogl[(size_t)d*16 + nidx]);
    float Dp = dprl[d];
    float h = 0.f;
    #pragma unroll 4
    for (int t = 0; t < TT; ++t){
      float dt = sdt[t*33 + dd];
      float xv = sxv[t*33 + dd];
      h = __expf(dt*A)*h + (dt*xv)*sB[t*18 + nidx];
      float yv = h * sC[t*18 + nidx];
      #pragma unroll
      for (int o = 8; o; o >>= 1) yv += __shfl_xor(yv, o, 64);
      if (nidx == 0) ygT[dd*36 + t] = (yv + Dp*xv) * szz[t*33 + dd];
    }
  }
  __syncthreads();
  // ---- stage opw slice [256 ch][32 k] transposed -> Wop[k][ch] ----
  {
    int c = tid >> 1, kh = tid & 1;
    const float4* src = (const float4*)(opwl + (size_t)c*DI + d0 + kh*16);
    #pragma unroll
    for (int q = 0; q < 4; ++q){
      float4 v = src[q];
      int k = kh*16 + q*4;
      Wop[(k+0)*260 + c] = v.x; Wop[(k+1)*260 + c] = v.y;
      Wop[(k+2)*260 + c] = v.z; Wop[(k+3)*260 + c] = v.w;
    }
  }
  __syncthreads();
  // ---- out_proj partial over K=32: each thread 4 t x 4 ch; atomic accumulate
  {
    int w = tid >> 6;                  // t-group 0..7
    int cq = (tid & 63)*4;             // channel base
    float acc[4][4] = {};
    #pragma unroll 4
    for (int k = 0; k < 32; ++k){
      vf4 xv = *(const vf4*)&ygT[k*36 + w*4];
      vf4 wv = *(const vf4*)&Wop[k*260 + cq];
      #pragma unroll
      for (int i = 0; i < 4; ++i){
        #pragma unroll
        for (int j = 0; j < 4; ++j) acc[i][j] += xv[i]*wv[j];
      }
    }
    #pragma unroll
    for (int i = 0; i < 4; ++i){
      size_t base = (size_t)(b*32 + w*4 + i)*DM + cq;
      #pragma unroll
      for (int j = 0; j < 4; ++j) atomicAdd(&accA[base + j], acc[i][j]);
    }
  }
}

// ---------------- CLS: final residual+LN (token 31) + classifier -------------
__global__ __launch_bounds__(128)
void k_cls(const float* __restrict__ feat3, const float* __restrict__ acc1,
           const float* __restrict__ ng, const float* __restrict__ nb,
           const float* __restrict__ w1, const float* __restrict__ b1,
           const float* __restrict__ w2, const float* __restrict__ b2,
           float* __restrict__ out)
{
  __shared__ float h[256];
  __shared__ float h1[128];
  int b = blockIdx.x, tid = threadIdx.x;
  if (tid < 64){
    int c4 = tid*4;
    size_t base = (size_t)(b*32 + 31)*DM + c4;
    float4 v = *(const float4*)&feat3[base];
    float4 u = *(const float4*)&acc1[base];
    v.x += u.x; v.y += u.y; v.z += u.z; v.w += u.w;
    float sm = v.x+v.y+v.z+v.w;
    float sq = v.x*v.x+v.y*v.y+v.z*v.z+v.w*v.w;
    #pragma unroll
    for (int o = 1; o < 64; o <<= 1){ sm += __shfl_xor(sm, o, 64); sq += __shfl_xor(sq, o, 64); }
    float mu = sm*(1.f/256.f), var = sq*(1.f/256.f) - mu*mu;
    float r = rsqrtf(var + 1e-5f);
    h[c4+0] = (v.x-mu)*r*ng[c4+0] + nb[c4+0];
    h[c4+1] = (v.y-mu)*r*ng[c4+1] + nb[c4+1];
    h[c4+2] = (v.z-mu)*r*ng[c4+2] + nb[c4+2];
    h[c4+3] = (v.w-mu)*r*ng[c4+3] + nb[c4+3];
  }
  __syncthreads();
  {
    float a = b1[tid];
    const float* wr = w1 + (size_t)tid*256;
    #pragma unroll 8
    for (int j = 0; j < 256; ++j) a += h[j]*wr[j];
    h1[tid] = fmaxf(a, 0.f);
  }
  __syncthreads();
  if (tid < 2){
    float a2 = b2[tid];
    const float* wr2 = w2 + (size_t)tid*128;
    #pragma unroll 8
    for (int j = 0; j < 128; ++j) a2 += h1[j]*wr2[j];
    out[b*2 + tid] = a2;
  }
}

extern "C" void kernel_launch(void* const* d_in, const int* in_sizes, int n_in,
                              void* d_out, int out_size, void* d_ws, size_t ws_size,
                              hipStream_t stream)
{
  const float* x   = (const float*)d_in[0];
  const float* ep  = (const float*)d_in[1];
  const float* ef  = (const float*)d_in[2];
  const float* ed  = (const float*)d_in[3];
  const float* plw = (const float*)d_in[4];
  const float* plb = (const float*)d_in[5];
  const float* piw = (const float*)d_in[6];
  const float* pib = (const float*)d_in[7];
  const float* fw  = (const float*)d_in[8];
  const float* fb  = (const float*)d_in[9];
  const float* tg  = (const float*)d_in[10];
  const float* tb  = (const float*)d_in[11];
  const float* ng  = (const float*)d_in[12];
  const float* nb  = (const float*)d_in[13];
  const float* ipw = (const float*)d_in[14];
  const float* cw  = (const float*)d_in[15];
  const float* cb  = (const float*)d_in[16];
  const float* xpw = (const float*)d_in[17];
  const float* dtw = (const float*)d_in[18];
  const float* dtb = (const float*)d_in[19];
  const float* alog= (const float*)d_in[20];
  const float* dpr = (const float*)d_in[21];
  const float* opw = (const float*)d_in[22];
  const float* w1  = (const float*)d_in[23];
  const float* b1  = (const float*)d_in[24];
  const float* w2  = (const float*)d_in[25];
  const float* b2  = (const float*)d_in[26];
  (void)in_sizes; (void)n_in; (void)out_size; (void)ws_size;

  float* ws    = (float*)d_ws;
  float* s0    = ws;                      // 131072
  float* featA = s0    + NTOK*DM;         // 131072
  float* featB = featA + NTOK*DM;         // 131072
  float* acc0  = featB + NTOK*DM;         // 131072
  float* acc1  = acc0  + NTOK*DM;         // 131072
  float* pxp   = acc1  + NTOK*DM;         // 16*8*48*32 = 196608
  float* xcT   = pxp   + 196608;          // 262144
  float* zsT   = xcT   + (size_t)DI*NTOK; // 262144
  float* accs[2]  = {acc0, acc1};
  float* fbufs[2] = {featA, featB};

  k_front<<<dim3(4,16),128,0,stream>>>(x, ep,ef,ed, plw,plb,piw,pib, fw,fb, s0);
  for (int ly = 0; ly < 4; ++ly){
    const float* gg = ly ? ng : tg;
    const float* gb = ly ? nb : tb;
    const float* resid = ly ? accs[(ly+1)&1] : s0;   // acc[(ly-1)&1]
    const float* fin   = ly ? fbufs[(ly+1)&1] : nullptr;
    k_ip<<<dim3(16,16),128,0,stream>>>(ipw + (size_t)ly*262144,
                                       cw + (size_t)ly*2048, cb + (size_t)ly*512,
                                       xpw + (size_t)ly*24576,
                                       gg, gb, resid, fin,
                                       fbufs[ly&1], accs[ly&1],
                                       pxp, xcT, zsT);
    k_sc<<<dim3(16,16),512,0,stream>>>(pxp,
                                       dtw + (size_t)ly*8192, dtb + (size_t)ly*512,
                                       alog + (size_t)ly*8192, dpr + (size_t)ly*512,
                                       opw + (size_t)ly*131072,
                                       xcT, zsT, accs[ly&1]);
  }
  k_cls<<<16,128,0,stream>>>(featB, acc1, ng, nb, w1, b1, w2, b2, (float*)d_out);
}

// Round 10
// 208.265 us; speedup vs baseline: 2.0002x; 2.0002x over previous
//
#include <hip/hip_runtime.h>
#include <cmath>

// BlockwiseEarlyExitMamba: output depends only on feat[:,31,:] -> compute T=32 tokens.
#define TT 32
#define NTOK 512   // BATCH*TT
#define DM 256
#define DI 512

typedef float vf4 __attribute__((ext_vector_type(4)));

__device__ __forceinline__ float silu_(float x){ return x / (1.f + __expf(-x)); }

#define FMA16() do { \
  acc[0][0] += xv.x*wv.x; acc[0][1] += xv.x*wv.y; acc[0][2] += xv.x*wv.z; acc[0][3] += xv.x*wv.w; \
  acc[1][0] += xv.y*wv.x; acc[1][1] += xv.y*wv.y; acc[1][2] += xv.y*wv.z; acc[1][3] += xv.y*wv.w; \
  acc[2][0] += xv.z*wv.x; acc[2][1] += xv.z*wv.y; acc[2][2] += xv.z*wv.z; acc[2][3] += xv.z*wv.w; \
  acc[3][0] += xv.w*wv.x; acc[3][1] += xv.w*wv.y; acc[3][2] += xv.w*wv.z; acc[3][3] += xv.w*wv.w; \
} while(0)

// ---------- frontend: embed -> fusion GEMM (K=136) -> raw s0 (verified r2) ---
__global__ __launch_bounds__(128)
void k_front(const float* __restrict__ x,
             const float* __restrict__ ep, const float* __restrict__ ef,
             const float* __restrict__ ed,
             const float* __restrict__ plw, const float* __restrict__ plb,
             const float* __restrict__ piw, const float* __restrict__ pib,
             const float* __restrict__ fw,  const float* __restrict__ fb,
             float* __restrict__ s0)
{
  __shared__ float Xs[136*36];
  __shared__ float Ws[136*68];
  int bb = blockIdx.y;
  int n0 = blockIdx.x*64;
  int tid = threadIdx.x;
  for (int r = 0; r < 34; ++r){
    int idx = r*128 + tid;
    int t = idx & 31, j = idx >> 5;
    const float* xr = x + ((size_t)(bb*1024 + t))*5;
    float v;
    if      (j <  32){ int i = __float2int_rz(xr[0]); i = min(max(i,0),255); v = ep[i*32 + j]; }
    else if (j <  64){ v = xr[1]*plw[j-32] + plb[j-32]; }
    else if (j <  96){ int i = __float2int_rz(xr[2]); i = min(max(i,0),63);  v = ef[i*32 + (j-64)]; }
    else if (j < 128){ v = xr[3]*piw[j-96] + pib[j-96]; }
    else             { int i = __float2int_rz(xr[4]); i = min(max(i,0),1);   v = ed[i*8 + (j-128)]; }
    Xs[j*36 + t] = v;
  }
  {
    int c = tid >> 1, jh = tid & 1;
    const float4* src = (const float4*)(fw + (size_t)(n0 + c)*136 + jh*68);
    #pragma unroll
    for (int q = 0; q < 17; ++q){
      float4 v = src[q];
      int j = jh*68 + q*4;
      Ws[(j+0)*68 + c] = v.x; Ws[(j+1)*68 + c] = v.y;
      Ws[(j+2)*68 + c] = v.z; Ws[(j+3)*68 + c] = v.w;
    }
  }
  __syncthreads();
  int my = tid >> 4, nx = tid & 15;
  float acc[4][4] = {};
  #pragma unroll 4
  for (int k = 0; k < 136; ++k){
    float4 xv = *(const float4*)&Xs[k*36 + my*4];
    float4 wv = *(const float4*)&Ws[k*68 + nx*4];
    FMA16();
  }
  #pragma unroll
  for (int i = 0; i < 4; ++i){
    int t = my*4 + i;
    float4 o;
    o.x = acc[i][0] + fb[n0 + nx*4 + 0];
    o.y = acc[i][1] + fb[n0 + nx*4 + 1];
    o.z = acc[i][2] + fb[n0 + nx*4 + 2];
    o.w = acc[i][3] + fb[n0 + nx*4 + 3];
    *(float4*)&s0[(size_t)(bb*32 + t)*DM + n0 + nx*4] = o;
  }
}

// ---------- residual sum (split-K parts) + LayerNorm -> feat (verified r2) ---
__global__ __launch_bounds__(64)
void k_rln(const float* __restrict__ p0, const float* __restrict__ p1,
           const float* __restrict__ p2, const float* __restrict__ p3,
           const float* __restrict__ base,
           const float* __restrict__ g, const float* __restrict__ b,
           float* __restrict__ feat)
{
  int p = blockIdx.x, tid = threadIdx.x;
  size_t off = (size_t)p*DM + tid*4;
  float4 v = *(const float4*)&p0[off];
  if (p1){ float4 a = *(const float4*)&p1[off]; v.x+=a.x; v.y+=a.y; v.z+=a.z; v.w+=a.w; }
  if (p2){ float4 a = *(const float4*)&p2[off]; v.x+=a.x; v.y+=a.y; v.z+=a.z; v.w+=a.w; }
  if (p3){ float4 a = *(const float4*)&p3[off]; v.x+=a.x; v.y+=a.y; v.z+=a.z; v.w+=a.w; }
  if (base){ float4 a = *(const float4*)&base[off]; v.x+=a.x; v.y+=a.y; v.z+=a.z; v.w+=a.w; }
  float s  = v.x + v.y + v.z + v.w;
  float sq = v.x*v.x + v.y*v.y + v.z*v.z + v.w*v.w;
  #pragma unroll
  for (int o = 1; o < 64; o <<= 1){ s += __shfl_xor(s, o, 64); sq += __shfl_xor(sq, o, 64); }
  float mu = s * (1.f/256.f);
  float var = sq * (1.f/256.f) - mu*mu;
  float r = rsqrtf(var + 1e-5f);
  float4 gg = *(const float4*)&g[tid*4];
  float4 bb = *(const float4*)&b[tid*4];
  float4 o;
  o.x = (v.x-mu)*r*gg.x + bb.x;
  o.y = (v.y-mu)*r*gg.y + bb.y;
  o.z = (v.z-mu)*r*gg.z + bb.z;
  o.w = (v.w-mu)*r*gg.w + bb.w;
  *(float4*)&feat[off] = o;
}

// ---------- in_proj GEMM: 16x64 tiles, grid (16 nt, 32 mt) = 512 blocks ------
__global__ __launch_bounds__(128)
void k_inproj(const float* __restrict__ feat, const float* __restrict__ w,
              float* __restrict__ xz)
{
  __shared__ float Xs[256*20];   // [k][t16 + pad4]
  __shared__ float Ws[64*68];
  int n0 = blockIdx.x*64, m0 = blockIdx.y*16;
  int tid = threadIdx.x;
  { // stage X tile: 16 tok x 256 k, transposed
    int t = tid & 15, kq = tid >> 4;     // kq 0..7
    const float4* src = (const float4*)(feat + (size_t)(m0+t)*DM + kq*32);
    #pragma unroll
    for (int q = 0; q < 8; ++q){
      float4 v = src[q];
      int k = kq*32 + q*4;
      Xs[(k+0)*20+t]=v.x; Xs[(k+1)*20+t]=v.y; Xs[(k+2)*20+t]=v.z; Xs[(k+3)*20+t]=v.w;
    }
  }
  int my = tid >> 4, nx = tid & 15;      // t = my*2+i, c = n0 + nx*4+j
  float acc[2][4] = {};
  for (int kc = 0; kc < 4; ++kc){
    __syncthreads();
    {
      int c = tid >> 1, kh = tid & 1;
      const float4* src = (const float4*)(w + (size_t)(n0+c)*DM + kc*64 + kh*32);
      #pragma unroll
      for (int q = 0; q < 8; ++q){
        float4 v = src[q];
        int k = kh*32 + q*4;
        Ws[(k+0)*68+c]=v.x; Ws[(k+1)*68+c]=v.y; Ws[(k+2)*68+c]=v.z; Ws[(k+3)*68+c]=v.w;
      }
    }
    __syncthreads();
    #pragma unroll 4
    for (int kk = 0; kk < 64; ++kk){
      float2 xv = *(const float2*)&Xs[(kc*64+kk)*20 + my*2];
      vf4  wv = *(const vf4*)&Ws[kk*68 + nx*4];
      acc[0][0] += xv.x*wv[0]; acc[0][1] += xv.x*wv[1];
      acc[0][2] += xv.x*wv[2]; acc[0][3] += xv.x*wv[3];
      acc[1][0] += xv.y*wv[0]; acc[1][1] += xv.y*wv[1];
      acc[1][2] += xv.y*wv[2]; acc[1][3] += xv.y*wv[3];
    }
  }
  #pragma unroll
  for (int i = 0; i < 2; ++i){
    float4 o = {acc[i][0], acc[i][1], acc[i][2], acc[i][3]};
    *(float4*)&xz[(size_t)(m0 + my*2 + i)*1024 + n0 + nx*4] = o;
  }
}

// ---------- conv + silu -> xc ; x_proj (wave-split) ; dt softplus (verified r2)
__global__ __launch_bounds__(512)
void k_conv(const float* __restrict__ xz,
            const float* __restrict__ cw, const float* __restrict__ cb,
            const float* __restrict__ xpw,
            const float* __restrict__ dtw, const float* __restrict__ dtb,
            float* __restrict__ xc, float* __restrict__ dtv,
            float* __restrict__ Bm, float* __restrict__ Cm)
{
  __shared__ float sxc[512];
  __shared__ float sdtr[16];
  __shared__ float sdtw[512*17];
  int p = blockIdx.x; int b = p >> 5, t = p & 31;
  int d = threadIdx.x;
  {
    const float4* src = (const float4*)(dtw + (size_t)d*16);
    #pragma unroll
    for (int q = 0; q < 4; ++q){
      float4 v = src[q]; int r = q*4;
      sdtw[d*17+r]=v.x; sdtw[d*17+r+1]=v.y; sdtw[d*17+r+2]=v.z; sdtw[d*17+r+3]=v.w;
    }
  }
  float a = cb[d];
  const float* cwr = cw + d*4;
  #pragma unroll
  for (int k = 0; k < 4; ++k){
    int tt = t - 3 + k;
    if (tt >= 0) a += cwr[k] * xz[((size_t)(b*TT + tt))*1024 + d];
  }
  float v = silu_(a);
  sxc[d] = v;
  xc[(size_t)p*DI + d] = v;
  __syncthreads();
  int wv_ = d >> 6, ln = d & 63;
  #pragma unroll
  for (int i = 0; i < 6; ++i){
    int c = wv_*6 + i;
    const float* wr = xpw + (size_t)c*512;
    float pa = 0.f;
    #pragma unroll
    for (int j = 0; j < 8; ++j) pa += wr[ln + 64*j] * sxc[ln + 64*j];
    #pragma unroll
    for (int o = 32; o; o >>= 1) pa += __shfl_down(pa, o, 64);
    if (ln == 0){
      if      (c < 16) sdtr[c] = pa;
      else if (c < 32) Bm[(size_t)p*16 + (c-16)] = pa;
      else             Cm[(size_t)p*16 + (c-32)] = pa;
    }
  }
  __syncthreads();
  float aa = dtb[d];
  #pragma unroll
  for (int r = 0; r < 16; ++r) aa += sdtr[r]*sdtw[d*17+r];
  dtv[(size_t)p*DI + d] = fmaxf(aa, 0.f) + log1pf(expf(-fabsf(aa)));
}

// ---------- selective scan (d,n parallel) + D-skip + gate -> yg --------------
// grid (16 ds of 32 d, 16 b), 512 thr = 32 d x 16 n; 8 waves/CU
__global__ __launch_bounds__(512)
void k_scan(const float* __restrict__ dtv, const float* __restrict__ xc,
            const float* __restrict__ xz,
            const float* __restrict__ Bm, const float* __restrict__ Cm,
            const float* __restrict__ alogl, const float* __restrict__ dprl,
            float* __restrict__ yg)
{
  __shared__ float sdt[32*34], sxv[32*34], szz[32*34];
  __shared__ float sB[32*18], sC[32*18];
  int tid = threadIdx.x;
  int ds = blockIdx.x, b = blockIdx.y;
  int d0 = ds*32;
  {
    int t = tid >> 4, q = (tid & 15)*2;
    size_t base = (size_t)(b*32 + t)*DI + d0 + q;
    *(float2*)&sdt[t*34 + q] = *(const float2*)&dtv[base];
    *(float2*)&sxv[t*34 + q] = *(const float2*)&xc[base];
    *(float2*)&szz[t*34 + q] = *(const float2*)&xz[(size_t)(b*32 + t)*1024 + 512 + d0 + q];
    if (tid < 256){
      int t2 = tid >> 3, n2 = (tid & 7)*2;
      size_t bb_ = (size_t)(b*32 + t2)*16 + n2;
      *(float2*)&sB[t2*18 + n2] = *(const float2*)&Bm[bb_];
      *(float2*)&sC[t2*18 + n2] = *(const float2*)&Cm[bb_];
    }
  }
  __syncthreads();
  int dd = tid >> 4, nidx = tid & 15;
  int d = d0 + dd;
  float A = -expf(alogl[(size_t)d*16 + nidx]);
  float Dp = dprl[d];
  float h = 0.f;
  #pragma unroll 4
  for (int t = 0; t < TT; ++t){
    float dt = sdt[t*34 + dd];
    float xv = sxv[t*34 + dd];
    h = __expf(dt*A)*h + (dt*xv)*sB[t*18 + nidx];
    float yv = h * sC[t*18 + nidx];
    #pragma unroll
    for (int o = 8; o; o >>= 1) yv += __shfl_xor(yv, o, 64);
    if (nidx == 0){
      float yo = (yv + Dp*xv) * silu_(szz[t*34 + dd]);
      yg[(size_t)(b*32 + t)*DI + d] = yo;
    }
  }
}

// ---------- out_proj split-K GEMM (yg pre-gated): tile 32x32, grid (8,16,4) --
__global__ __launch_bounds__(128)
void k_outproj(const float* __restrict__ yg, const float* __restrict__ w,
               float* __restrict__ parts)
{
  __shared__ float Xs[128*34];   // [k][t32 + pad2]
  __shared__ float Ws[128*36];   // [k][c32 + pad4]
  int n0 = blockIdx.x*32, m0 = blockIdx.y*32, kz = blockIdx.z;
  int k0 = kz*128;
  int tid = threadIdx.x;
  {
    int t = tid >> 2, kq = tid & 3;
    const float4* src = (const float4*)(yg + (size_t)(m0+t)*DI + k0 + kq*32);
    #pragma unroll
    for (int q = 0; q < 8; ++q){
      float4 v = src[q];
      int k = kq*32 + q*4;
      Xs[(k+0)*34+t]=v.x; Xs[(k+1)*34+t]=v.y; Xs[(k+2)*34+t]=v.z; Xs[(k+3)*34+t]=v.w;
    }
  }
  {
    int c = tid >> 2, kh = tid & 3;
    const float4* src = (const float4*)(w + (size_t)(n0+c)*DI + k0 + kh*32);
    #pragma unroll
    for (int q = 0; q < 8; ++q){
      float4 v = src[q];
      int k = kh*32 + q*4;
      Ws[(k+0)*36+c]=v.x; Ws[(k+1)*36+c]=v.y; Ws[(k+2)*36+c]=v.z; Ws[(k+3)*36+c]=v.w;
    }
  }
  __syncthreads();
  int my = tid >> 3, nx = tid & 7;   // t = my*2+i, c = n0 + nx*4+j
  float acc[2][4] = {};
  #pragma unroll 4
  for (int kk = 0; kk < 128; ++kk){
    float2 xv = *(const float2*)&Xs[kk*34 + my*2];
    vf4  wv = *(const vf4*)&Ws[kk*36 + nx*4];
    acc[0][0] += xv.x*wv[0]; acc[0][1] += xv.x*wv[1];
    acc[0][2] += xv.x*wv[2]; acc[0][3] += xv.x*wv[3];
    acc[1][0] += xv.y*wv[0]; acc[1][1] += xv.y*wv[1];
    acc[1][2] += xv.y*wv[2]; acc[1][3] += xv.y*wv[3];
  }
  float* dst = parts + (size_t)kz*NTOK*DM;
  #pragma unroll
  for (int i = 0; i < 2; ++i){
    float4 o = {acc[i][0], acc[i][1], acc[i][2], acc[i][3]};
    *(float4*)&dst[(size_t)(m0 + my*2 + i)*DM + n0 + nx*4] = o;
  }
}

// ---------- classifier on token 31 (verified r2) -----------------------------
__global__ __launch_bounds__(128)
void k_cls(const float* __restrict__ feat,
           const float* __restrict__ w1, const float* __restrict__ b1,
           const float* __restrict__ w2, const float* __restrict__ b2,
           float* __restrict__ out)
{
  __shared__ float h[256];
  __shared__ float h1[128];
  int b = blockIdx.x;
  int tid = threadIdx.x;
  const float* fr = feat + ((size_t)(b*TT + 31))*DM;
  h[tid]       = fr[tid];
  h[tid + 128] = fr[tid + 128];
  __syncthreads();
  float a = b1[tid];
  const float* wr = w1 + (size_t)tid*256;
  #pragma unroll 8
  for (int j = 0; j < 256; ++j) a += h[j]*wr[j];
  h1[tid] = fmaxf(a, 0.f);
  __syncthreads();
  if (tid < 2){
    float a2 = b2[tid];
    const float* wr2 = w2 + (size_t)tid*128;
    #pragma unroll 8
    for (int j = 0; j < 128; ++j) a2 += h1[j]*wr2[j];
    out[b*2 + tid] = a2;
  }
}

extern "C" void kernel_launch(void* const* d_in, const int* in_sizes, int n_in,
                              void* d_out, int out_size, void* d_ws, size_t ws_size,
                              hipStream_t stream)
{
  const float* x   = (const float*)d_in[0];
  const float* ep  = (const float*)d_in[1];
  const float* ef  = (const float*)d_in[2];
  const float* ed  = (const float*)d_in[3];
  const float* plw = (const float*)d_in[4];
  const float* plb = (const float*)d_in[5];
  const float* piw = (const float*)d_in[6];
  const float* pib = (const float*)d_in[7];
  const float* fw  = (const float*)d_in[8];
  const float* fb  = (const float*)d_in[9];
  const float* tg  = (const float*)d_in[10];
  const float* tb  = (const float*)d_in[11];
  const float* ng  = (const float*)d_in[12];
  const float* nb  = (const float*)d_in[13];
  const float* ipw = (const float*)d_in[14];
  const float* cw  = (const float*)d_in[15];
  const float* cb  = (const float*)d_in[16];
  const float* xpw = (const float*)d_in[17];
  const float* dtw = (const float*)d_in[18];
  const float* dtb = (const float*)d_in[19];
  const float* alog= (const float*)d_in[20];
  const float* dpr = (const float*)d_in[21];
  const float* opw = (const float*)d_in[22];
  const float* w1  = (const float*)d_in[23];
  const float* b1  = (const float*)d_in[24];
  const float* w2  = (const float*)d_in[25];
  const float* b2  = (const float*)d_in[26];
  (void)in_sizes; (void)n_in; (void)out_size; (void)ws_size;

  float* ws    = (float*)d_ws;
  float* feat  = ws;                       // 131072
  float* xz    = feat + NTOK*DM;           // 524288
  float* xc    = xz   + NTOK*1024;         // 262144
  float* dtv   = xc   + NTOK*DI;           // 262144
  float* Bm    = dtv  + NTOK*DI;           // 8192
  float* Cm    = Bm   + NTOK*16;           // 8192
  float* yg    = Cm   + NTOK*16;           // 262144
  float* parts = yg   + NTOK*DI;           // 4*131072
  float* s0    = parts + 4*NTOK*DM;        // 131072

  const size_t PS = (size_t)NTOK*DM;

  k_front<<<dim3(4,16),128,0,stream>>>(x, ep,ef,ed, plw,plb,piw,pib, fw,fb, s0);
  k_rln<<<NTOK,64,0,stream>>>(s0, nullptr,nullptr,nullptr, nullptr, tg, tb, feat);

  for (int ly = 0; ly < 4; ++ly){
    k_inproj<<<dim3(16,32),128,0,stream>>>(feat, ipw + (size_t)ly*262144, xz);
    k_conv<<<NTOK,512,0,stream>>>(xz, cw + (size_t)ly*2048, cb + (size_t)ly*512,
                                  xpw + (size_t)ly*24576,
                                  dtw + (size_t)ly*8192, dtb + (size_t)ly*512,
                                  xc, dtv, Bm, Cm);
    k_scan<<<dim3(16,16),512,0,stream>>>(dtv, xc, xz, Bm, Cm,
                                         alog + (size_t)ly*8192, dpr + (size_t)ly*512,
                                         yg);
    k_outproj<<<dim3(8,16,4),128,0,stream>>>(yg, opw + (size_t)ly*131072, parts);
    k_rln<<<NTOK,64,0,stream>>>(parts, parts+PS, parts+2*PS, parts+3*PS,
                                feat, ng, nb, feat);
  }
  k_cls<<<16,128,0,stream>>>(feat, w1, b1, w2, b2, (float*)d_out);
}

// Round 11
// 193.247 us; speedup vs baseline: 2.1556x; 1.0777x over previous
//
#include <hip/hip_runtime.h>
#include <cmath>

// BlockwiseEarlyExitMamba: output depends only on feat[:,31,:] -> compute T=32 tokens.
#define TT 32
#define NTOK 512   // BATCH*TT
#define DM 256
#define DI 512

typedef float vf4 __attribute__((ext_vector_type(4)));

__device__ __forceinline__ float silu_(float x){ return x / (1.f + __expf(-x)); }

#define FMA16() do { \
  acc[0][0] += xv.x*wv.x; acc[0][1] += xv.x*wv.y; acc[0][2] += xv.x*wv.z; acc[0][3] += xv.x*wv.w; \
  acc[1][0] += xv.y*wv.x; acc[1][1] += xv.y*wv.y; acc[1][2] += xv.y*wv.z; acc[1][3] += xv.y*wv.w; \
  acc[2][0] += xv.z*wv.x; acc[2][1] += xv.z*wv.y; acc[2][2] += xv.z*wv.z; acc[2][3] += xv.z*wv.w; \
  acc[3][0] += xv.w*wv.x; acc[3][1] += xv.w*wv.y; acc[3][2] += xv.w*wv.z; acc[3][3] += xv.w*wv.w; \
} while(0)

// ---------- frontend: embed -> fusion GEMM (K=136) -> raw s0 (verified r2) ---
__global__ __launch_bounds__(128)
void k_front(const float* __restrict__ x,
             const float* __restrict__ ep, const float* __restrict__ ef,
             const float* __restrict__ ed,
             const float* __restrict__ plw, const float* __restrict__ plb,
             const float* __restrict__ piw, const float* __restrict__ pib,
             const float* __restrict__ fw,  const float* __restrict__ fb,
             float* __restrict__ s0)
{
  __shared__ float Xs[136*36];
  __shared__ float Ws[136*68];
  int bb = blockIdx.y;
  int n0 = blockIdx.x*64;
  int tid = threadIdx.x;
  for (int r = 0; r < 34; ++r){
    int idx = r*128 + tid;
    int t = idx & 31, j = idx >> 5;
    const float* xr = x + ((size_t)(bb*1024 + t))*5;
    float v;
    if      (j <  32){ int i = __float2int_rz(xr[0]); i = min(max(i,0),255); v = ep[i*32 + j]; }
    else if (j <  64){ v = xr[1]*plw[j-32] + plb[j-32]; }
    else if (j <  96){ int i = __float2int_rz(xr[2]); i = min(max(i,0),63);  v = ef[i*32 + (j-64)]; }
    else if (j < 128){ v = xr[3]*piw[j-96] + pib[j-96]; }
    else             { int i = __float2int_rz(xr[4]); i = min(max(i,0),1);   v = ed[i*8 + (j-128)]; }
    Xs[j*36 + t] = v;
  }
  {
    int c = tid >> 1, jh = tid & 1;
    const float4* src = (const float4*)(fw + (size_t)(n0 + c)*136 + jh*68);
    #pragma unroll
    for (int q = 0; q < 17; ++q){
      float4 v = src[q];
      int j = jh*68 + q*4;
      Ws[(j+0)*68 + c] = v.x; Ws[(j+1)*68 + c] = v.y;
      Ws[(j+2)*68 + c] = v.z; Ws[(j+3)*68 + c] = v.w;
    }
  }
  __syncthreads();
  int my = tid >> 4, nx = tid & 15;
  float acc[4][4] = {};
  #pragma unroll 4
  for (int k = 0; k < 136; ++k){
    float4 xv = *(const float4*)&Xs[k*36 + my*4];
    float4 wv = *(const float4*)&Ws[k*68 + nx*4];
    FMA16();
  }
  #pragma unroll
  for (int i = 0; i < 4; ++i){
    int t = my*4 + i;
    float4 o;
    o.x = acc[i][0] + fb[n0 + nx*4 + 0];
    o.y = acc[i][1] + fb[n0 + nx*4 + 1];
    o.z = acc[i][2] + fb[n0 + nx*4 + 2];
    o.w = acc[i][3] + fb[n0 + nx*4 + 3];
    *(float4*)&s0[(size_t)(bb*32 + t)*DM + n0 + nx*4] = o;
  }
}

// ---------- token LayerNorm (verified r2) ------------------------------------
__global__ __launch_bounds__(64)
void k_rln(const float* __restrict__ p0, const float* __restrict__ g,
           const float* __restrict__ b, float* __restrict__ feat)
{
  int p = blockIdx.x, tid = threadIdx.x;
  size_t off = (size_t)p*DM + tid*4;
  float4 v = *(const float4*)&p0[off];
  float s  = v.x + v.y + v.z + v.w;
  float sq = v.x*v.x + v.y*v.y + v.z*v.z + v.w*v.w;
  #pragma unroll
  for (int o = 1; o < 64; o <<= 1){ s += __shfl_xor(s, o, 64); sq += __shfl_xor(sq, o, 64); }
  float mu = s * (1.f/256.f);
  float var = sq * (1.f/256.f) - mu*mu;
  float r = rsqrtf(var + 1e-5f);
  float4 gg = *(const float4*)&g[tid*4];
  float4 bb = *(const float4*)&b[tid*4];
  float4 o;
  o.x = (v.x-mu)*r*gg.x + bb.x;
  o.y = (v.y-mu)*r*gg.y + bb.y;
  o.z = (v.z-mu)*r*gg.z + bb.z;
  o.w = (v.w-mu)*r*gg.w + bb.w;
  *(float4*)&feat[off] = o;
}

// ---------- 16-part residual sum + LayerNorm -> feat -------------------------
__global__ __launch_bounds__(64)
void k_rln16(const float* __restrict__ parts, const float* __restrict__ featIn,
             const float* __restrict__ g, const float* __restrict__ b,
             float* __restrict__ feat)
{
  int p = blockIdx.x, tid = threadIdx.x;
  size_t off = (size_t)p*DM + tid*4;
  float4 v = *(const float4*)&parts[off];
  #pragma unroll
  for (int q = 1; q < 16; ++q){
    float4 a = *(const float4*)&parts[(size_t)q*NTOK*DM + off];
    v.x+=a.x; v.y+=a.y; v.z+=a.z; v.w+=a.w;
  }
  { float4 a = *(const float4*)&featIn[off]; v.x+=a.x; v.y+=a.y; v.z+=a.z; v.w+=a.w; }
  float s  = v.x + v.y + v.z + v.w;
  float sq = v.x*v.x + v.y*v.y + v.z*v.z + v.w*v.w;
  #pragma unroll
  for (int o = 1; o < 64; o <<= 1){ s += __shfl_xor(s, o, 64); sq += __shfl_xor(sq, o, 64); }
  float mu = s * (1.f/256.f);
  float var = sq * (1.f/256.f) - mu*mu;
  float r = rsqrtf(var + 1e-5f);
  float4 gg = *(const float4*)&g[tid*4];
  float4 bb = *(const float4*)&b[tid*4];
  float4 o;
  o.x = (v.x-mu)*r*gg.x + bb.x;
  o.y = (v.y-mu)*r*gg.y + bb.y;
  o.z = (v.z-mu)*r*gg.z + bb.z;
  o.w = (v.w-mu)*r*gg.w + bb.w;
  *(float4*)&feat[off] = o;
}

// ---------- k_A: in_proj GEMM + conv/silu + x_proj partials ------------------
// grid (16 nt, 16 b), 512 thr, dyn LDS 71680B. nt<8: x-channels, nt>=8: z.
// GEMM: wave-uniform X broadcast (4 tok) x stride-1 W (64 ch) -> VALU-bound.
__global__ __launch_bounds__(512)
void k_A(const float* __restrict__ wip, const float* __restrict__ cwl,
         const float* __restrict__ cbl, const float* __restrict__ xpl,
         const float* __restrict__ feat,
         float* __restrict__ xc, float* __restrict__ zs, float* __restrict__ pxp)
{
  extern __shared__ float lds[];
  float* Xs  = lds;            // [256][36] = 9216
  float* Ws  = lds + 9216;     // [64][68]  = 4352
  float* sxz = lds + 13568;    // [32][65]  = 2080
  float* xcl = lds + 15648;    // [32][65]  = 2080   total 17728 floats
  int tid = threadIdx.x;
  int nt = blockIdx.x, b = blockIdx.y;
  int n0 = nt*64;

  { // stage Xs [k][t] from feat, coalesced (16 lanes x 16B consecutive)
    int t = tid >> 4, kq = tid & 15;
    const float4* src = (const float4*)(feat + (size_t)(b*32 + t)*DM);
    #pragma unroll
    for (int q = 0; q < 4; ++q){
      float4 v = src[q*16 + kq];
      int k = (q*16 + kq)*4;
      Xs[(k+0)*36 + t] = v.x; Xs[(k+1)*36 + t] = v.y;
      Xs[(k+2)*36 + t] = v.z; Xs[(k+3)*36 + t] = v.w;
    }
  }
  int tg = tid >> 6, cc = tid & 63;    // tokens tg*4..+3, channel n0+cc
  float a0 = 0.f, a1 = 0.f, a2 = 0.f, a3 = 0.f;
  for (int kc = 0; kc < 4; ++kc){
    __syncthreads();
    { // stage Ws chunk [64k][64c+pad]
      int c = tid >> 3, kh = tid & 7;
      const float4* src = (const float4*)(wip + (size_t)(n0+c)*DM + kc*64 + kh*8);
      #pragma unroll
      for (int q = 0; q < 2; ++q){
        float4 v = src[q];
        int k = kh*8 + q*4;
        Ws[(k+0)*68 + c] = v.x; Ws[(k+1)*68 + c] = v.y;
        Ws[(k+2)*68 + c] = v.z; Ws[(k+3)*68 + c] = v.w;
      }
    }
    __syncthreads();
    #pragma unroll 8
    for (int kk = 0; kk < 64; ++kk){
      vf4 xv = *(const vf4*)&Xs[(kc*64 + kk)*36 + tg*4];   // wave-uniform broadcast
      float wv = Ws[kk*68 + cc];                           // stride-1, conflict-free
      a0 += xv[0]*wv; a1 += xv[1]*wv; a2 += xv[2]*wv; a3 += xv[3]*wv;
    }
  }
  __syncthreads();
  sxz[(tg*4+0)*65 + cc] = a0;
  sxz[(tg*4+1)*65 + cc] = a1;
  sxz[(tg*4+2)*65 + cc] = a2;
  sxz[(tg*4+3)*65 + cc] = a3;
  __syncthreads();

  { // conv+silu (x) / silu (z); coalesced float4 global stores
    int t = tid >> 4, c4 = (tid & 15)*4;
    float rr[4];
    if (n0 < 512){
      #pragma unroll
      for (int j = 0; j < 4; ++j){
        int c = c4 + j, d = n0 + c;
        float4 k4 = *(const float4*)(cwl + (size_t)d*4);
        float a = cbl[d];
        if (t >= 3) a += k4.x*sxz[(t-3)*65 + c];
        if (t >= 2) a += k4.y*sxz[(t-2)*65 + c];
        if (t >= 1) a += k4.z*sxz[(t-1)*65 + c];
        a += k4.w*sxz[t*65 + c];
        rr[j] = silu_(a);
        xcl[t*65 + c] = rr[j];
      }
      float4 o = {rr[0], rr[1], rr[2], rr[3]};
      *(float4*)&xc[(size_t)(b*32 + t)*DI + n0 + c4] = o;
    } else {
      #pragma unroll
      for (int j = 0; j < 4; ++j) rr[j] = silu_(sxz[t*65 + c4 + j]);
      float4 o = {rr[0], rr[1], rr[2], rr[3]};
      *(float4*)&zs[(size_t)(b*32 + t)*DI + (n0 - 512) + c4] = o;
    }
  }
  if (n0 < 512){
    __syncthreads();
    // x_proj partials over this block's 64 dims: 8 waves x 6 ch
    int w = tid >> 6, ln = tid & 63;
    int tt = ln & 31, half = ln >> 5;
    #pragma unroll
    for (int j = 0; j < 6; ++j){
      int c = w*6 + j;
      const float* wr = xpl + (size_t)c*DI + n0 + half*32;
      const float* xr = xcl + tt*65 + half*32;
      float pa = 0.f;
      #pragma unroll 8
      for (int q = 0; q < 32; ++q) pa += wr[q]*xr[q];
      pa += __shfl_xor(pa, 32, 64);
      if (half == 0) pxp[((size_t)(b*8 + nt)*48 + c)*32 + tt] = pa;
    }
  }
}

// ---------- k_sc: xp-reduce + dt + scan + gate + out_proj partial ------------
// grid (16 ds of 32 d, 16 b), 512 thr. (round-9 verified core, atomic->stores)
__global__ __launch_bounds__(512)
void k_sc(const float* __restrict__ pxp,
          const float* __restrict__ dtwl, const float* __restrict__ dtbl,
          const float* __restrict__ alogl, const float* __restrict__ dprl,
          const float* __restrict__ opwl,
          const float* __restrict__ xc, const float* __restrict__ zs,
          float* __restrict__ parts)
{
  __shared__ float sdtr[32*18], sB[32*18], sC[32*18];
  __shared__ float sdt[32*33], sxv[32*33], szz[32*33];
  __shared__ float ygT[32*36];
  __shared__ float Wop[32*260];
  int tid = threadIdx.x;
  int ds = blockIdx.x, b = blockIdx.y;
  int d0 = ds*32;

  // ---- sum 8 x_proj partials -> dtr/B/C (round-9 verified) ----
  #pragma unroll
  for (int r = 0; r < 3; ++r){
    int o = r*512 + tid;
    int c = o >> 5, t = o & 31;
    size_t p0 = ((size_t)(b*8)*48 + c)*32 + t;
    float v = 0.f;
    #pragma unroll
    for (int nb = 0; nb < 8; ++nb) v += pxp[p0 + (size_t)nb*1536];
    if      (c < 16) sdtr[t*18 + c] = v;
    else if (c < 32) sB[t*18 + (c-16)] = v;
    else             sC[t*18 + (c-32)] = v;
  }
  // ---- stage xv, zz slices from [tok][d] buffers ----
  {
    int t = tid >> 4, q = (tid & 15)*2;
    size_t base = (size_t)(b*32 + t)*DI + d0 + q;
    float2 u = *(const float2*)&xc[base];
    float2 w = *(const float2*)&zs[base];
    sxv[t*33 + q] = u.x; sxv[t*33 + q + 1] = u.y;
    szz[t*33 + q] = w.x; szz[t*33 + q + 1] = w.y;
  }
  __syncthreads();
  // ---- dt = softplus(dtr @ dtw.T + dtb) (round-9 verified) ----
  #pragma unroll
  for (int r = 0; r < 2; ++r){
    int idx = tid*2 + r;
    int t = idx >> 5, dl = idx & 31;
    int d = d0 + dl;
    const float4* dwr = (const float4*)(dtwl + (size_t)d*16);
    float4 w0 = dwr[0], w1 = dwr[1], w2 = dwr[2], w3 = dwr[3];
    const float* sr = &sdtr[t*18];
    float a = dtbl[d];
    a += w0.x*sr[0] + w0.y*sr[1] + w0.z*sr[2] + w0.w*sr[3];
    a += w1.x*sr[4] + w1.y*sr[5] + w1.z*sr[6] + w1.w*sr[7];
    a += w2.x*sr[8] + w2.y*sr[9] + w2.z*sr[10]+ w2.w*sr[11];
    a += w3.x*sr[12]+ w3.y*sr[13]+ w3.z*sr[14]+ w3.w*sr[15];
    sdt[t*33 + dl] = fmaxf(a, 0.f) + log1pf(expf(-fabsf(a)));
  }
  __syncthreads();
  // ---- scan (32 d x 16 n) + D-skip + gate -> ygT (round-9/10 verified) ----
  {
    int dd = tid >> 4, nidx = tid & 15;
    int d = d0 + dd;
    float A = -expf(alogl[(size_t)d*16 + nidx]);
    float Dp = dprl[d];
    float h = 0.f;
    #pragma unroll 4
    for (int t = 0; t < TT; ++t){
      float dt = sdt[t*33 + dd];
      float xv = sxv[t*33 + dd];
      h = __expf(dt*A)*h + (dt*xv)*sB[t*18 + nidx];
      float yv = h * sC[t*18 + nidx];
      #pragma unroll
      for (int o = 8; o; o >>= 1) yv += __shfl_xor(yv, o, 64);
      if (nidx == 0) ygT[dd*36 + t] = (yv + Dp*xv) * szz[t*33 + dd];
    }
  }
  __syncthreads();
  // ---- stage opw slice [256 ch][32 k] transposed (round-9 verified) ----
  {
    int c = tid >> 1, kh = tid & 1;
    const float4* src = (const float4*)(opwl + (size_t)c*DI + d0 + kh*16);
    #pragma unroll
    for (int q = 0; q < 4; ++q){
      float4 v = src[q];
      int k = kh*16 + q*4;
      Wop[(k+0)*260 + c] = v.x; Wop[(k+1)*260 + c] = v.y;
      Wop[(k+2)*260 + c] = v.z; Wop[(k+3)*260 + c] = v.w;
    }
  }
  __syncthreads();
  // ---- out_proj partial over K=32 -> parts[ds] (plain stores) ----
  {
    int w = tid >> 6;
    int cq = (tid & 63)*4;
    float acc[4][4] = {};
    #pragma unroll 4
    for (int k = 0; k < 32; ++k){
      vf4 xv = *(const vf4*)&ygT[k*36 + w*4];
      vf4 wv = *(const vf4*)&Wop[k*260 + cq];
      #pragma unroll
      for (int i = 0; i < 4; ++i){
        #pragma unroll
        for (int j = 0; j < 4; ++j) acc[i][j] += xv[i]*wv[j];
      }
    }
    float* dst = parts + (size_t)ds*NTOK*DM;
    #pragma unroll
    for (int i = 0; i < 4; ++i){
      float4 o = {acc[i][0], acc[i][1], acc[i][2], acc[i][3]};
      *(float4*)&dst[(size_t)(b*32 + w*4 + i)*DM + cq] = o;
    }
  }
}

// ---------- classifier on token 31 (verified r2) -----------------------------
__global__ __launch_bounds__(128)
void k_cls(const float* __restrict__ feat,
           const float* __restrict__ w1, const float* __restrict__ b1,
           const float* __restrict__ w2, const float* __restrict__ b2,
           float* __restrict__ out)
{
  __shared__ float h[256];
  __shared__ float h1[128];
  int b = blockIdx.x;
  int tid = threadIdx.x;
  const float* fr = feat + ((size_t)(b*TT + 31))*DM;
  h[tid]       = fr[tid];
  h[tid + 128] = fr[tid + 128];
  __syncthreads();
  float a = b1[tid];
  const float* wr = w1 + (size_t)tid*256;
  #pragma unroll 8
  for (int j = 0; j < 256; ++j) a += h[j]*wr[j];
  h1[tid] = fmaxf(a, 0.f);
  __syncthreads();
  if (tid < 2){
    float a2 = b2[tid];
    const float* wr2 = w2 + (size_t)tid*128;
    #pragma unroll 8
    for (int j = 0; j < 128; ++j) a2 += h1[j]*wr2[j];
    out[b*2 + tid] = a2;
  }
}

extern "C" void kernel_launch(void* const* d_in, const int* in_sizes, int n_in,
                              void* d_out, int out_size, void* d_ws, size_t ws_size,
                              hipStream_t stream)
{
  const float* x   = (const float*)d_in[0];
  const float* ep  = (const float*)d_in[1];
  const float* ef  = (const float*)d_in[2];
  const float* ed  = (const float*)d_in[3];
  const float* plw = (const float*)d_in[4];
  const float* plb = (const float*)d_in[5];
  const float* piw = (const float*)d_in[6];
  const float* pib = (const float*)d_in[7];
  const float* fw  = (const float*)d_in[8];
  const float* fb  = (const float*)d_in[9];
  const float* tg  = (const float*)d_in[10];
  const float* tb  = (const float*)d_in[11];
  const float* ng  = (const float*)d_in[12];
  const float* nb  = (const float*)d_in[13];
  const float* ipw = (const float*)d_in[14];
  const float* cw  = (const float*)d_in[15];
  const float* cb  = (const float*)d_in[16];
  const float* xpw = (const float*)d_in[17];
  const float* dtw = (const float*)d_in[18];
  const float* dtb = (const float*)d_in[19];
  const float* alog= (const float*)d_in[20];
  const float* dpr = (const float*)d_in[21];
  const float* opw = (const float*)d_in[22];
  const float* w1  = (const float*)d_in[23];
  const float* b1  = (const float*)d_in[24];
  const float* w2  = (const float*)d_in[25];
  const float* b2  = (const float*)d_in[26];
  (void)in_sizes; (void)n_in; (void)out_size; (void)ws_size;

  float* ws    = (float*)d_ws;
  float* feat  = ws;                       // 131072
  float* s0    = feat + NTOK*DM;           // 131072
  float* xc    = s0   + NTOK*DM;           // 262144
  float* zs    = xc   + NTOK*DI;           // 262144
  float* pxp   = zs   + NTOK*DI;           // 196608
  float* parts = pxp  + 196608;            // 16*131072 = 2097152

  k_front<<<dim3(4,16),128,0,stream>>>(x, ep,ef,ed, plw,plb,piw,pib, fw,fb, s0);
  k_rln<<<NTOK,64,0,stream>>>(s0, tg, tb, feat);

  for (int ly = 0; ly < 4; ++ly){
    k_A<<<dim3(16,16),512,71680,stream>>>(ipw + (size_t)ly*262144,
                                          cw + (size_t)ly*2048, cb + (size_t)ly*512,
                                          xpw + (size_t)ly*24576,
                                          feat, xc, zs, pxp);
    k_sc<<<dim3(16,16),512,0,stream>>>(pxp,
                                       dtw + (size_t)ly*8192, dtb + (size_t)ly*512,
                                       alog + (size_t)ly*8192, dpr + (size_t)ly*512,
                                       opw + (size_t)ly*131072,
                                       xc, zs, parts);
    k_rln16<<<NTOK,64,0,stream>>>(parts, feat, ng, nb, feat);
  }
  k_cls<<<16,128,0,stream>>>(feat, w1, b1, w2, b2, (float*)d_out);
}